// Round 1
// baseline (269.215 us; speedup 1.0000x reference)
//
#include <hip/hip_runtime.h>
#include <hip/hip_bf16.h>
#include <math.h>

#define VN 20000
#define JN 24
#define TILE 64
#define KP 132            // packed-activation row pitch in dwords (unchanged)
#define EPSF 1e-8f

typedef __attribute__((ext_vector_type(8))) short bfrag;   // 8 bf16 = 4 VGPRs
typedef __attribute__((ext_vector_type(4))) float f32x4;

// per-joint bf16 weight-plane offsets (ushort units) — round-8 doubled-K layout.
// ext slot k_ext = 2*k + {0:hi,1:lo} of the activation. Per layer, TWO B planes:
//   plane A: B[2k]=B[2k+1]=w_hi[k]   -> (ah+al)*bh
//   plane B: B[2k]=w_lo[k], B[2k+1]=0 -> ah*bl
// Sum = ah*bh + al*bh + ah*bl  == the previous 3-mfma scheme, with zero perms.
#define WJ_STRIDE 139264
#define L0A 0
#define L0B 4096
#define L1A 8192
#define L1B 40960
#define L2A 73728
#define L2B 106496

__device__ __forceinline__ unsigned short f2bf(float x) {
    __hip_bfloat16 b = __float2bfloat16(x);
    unsigned short u; __builtin_memcpy(&u, &b, 2); return u;
}
__device__ __forceinline__ float bf2f(unsigned short u) {
    __hip_bfloat16 b; __builtin_memcpy(&b, &u, 2);
    return __bfloat162float(b);
}
// pack hi|lo bf16 into one dword: low16 = bf16(x) (exact convert of the
// half-up-rounded hi), high16 = bf16(x - hi) (RTNE via v_cvt_pk). 4 VALU ops.
__device__ __forceinline__ unsigned int pack_hl(float x) {
    const unsigned int h = (__float_as_uint(x) + 0x8000u) & 0xffff0000u;
    const float hf = __uint_as_float(h);
    const float lo = x - hf;
    unsigned int r;
    asm("v_cvt_pk_bf16_f32 %0, %1, %2" : "=v"(r) : "v"(hf), "v"(lo));
    return r;
}

// softplus(100x)/100 with ONE transcendental: max(x,0) + q(u), u = 2^(-144.27|x|).
// q = 0.01*log1p-minimax; coeffs are the exact y=2u-1 re-base of the validated
// deg-5 poly (q(1)=0.00693152 vs ln2/100=0.00693147). 9 VALU ops total.
__device__ __forceinline__ float softplus_fast(float x) {
    const float u = __builtin_amdgcn_exp2f(-144.269504f * fabsf(x));
    float p = fmaf(u, 3.04480e-4f, -1.31584e-3f);
    p = fmaf(u, p, 2.852768e-3f);
    p = fmaf(u, p, -4.902308e-3f);
    p = fmaf(u, p, 9.992342e-3f);
    p = fmaf(u, p, 8.0e-8f);
    return fmaxf(x, 0.0f) + p;
}

// ---------------------------------------------------------------------------
// Kernel 1: per-joint prep (unchanged structure, 384 threads)
// ---------------------------------------------------------------------------
__global__ __launch_bounds__(384) void prep_kernel(
    const float* __restrict__ Bcond, const float* __restrict__ Bneigh,
    const float* __restrict__ ralpha, const float* __restrict__ rbeta,
    const float* __restrict__ cW0, const float* __restrict__ cb0,
    const float* __restrict__ cW1, const float* __restrict__ cb1,
    const float* __restrict__ cW2, const float* __restrict__ cb2,
    float* __restrict__ c4, float* __restrict__ geom)
{
    __shared__ float hbuf[JN][16];
    const int t = threadIdx.x;

    if (t < JN * 2) {
        const int j = t >> 1, gi = t & 1;
        const float* nb = Bneigh + (j * 2 + gi) * 15;
        const float tx = nb[0],  ty = nb[1],  tz = nb[2];
        const float cx = nb[3],  cy = nb[4],  cz = nb[5];
        const float ox = nb[6],  oy = nb[7],  oz = nb[8];
        const float px = nb[9],  py = nb[10], pz = nb[11];
        const int bid_this  = (int)nb[12];
        const int bid_other = (int)nb[13];
        const float xa_n = ralpha[bid_other * JN + bid_this] - 1.0f;
        const float xa_s = ralpha[bid_this * JN + bid_other] - 1.0f;
        const float a_n = xa_n > 0.0f ? xa_n + 1.0f : expf(xa_n);
        const float a_s = xa_s > 0.0f ? xa_s + 1.0f : expf(xa_s);
        const float be_n = rbeta[bid_other * JN + bid_this];
        const float be_s = rbeta[bid_this * JN + bid_other];

        const float bnx = ox - cx, bny = oy - cy, bnz = oz - cz;
        const float bsx = tx - cx, bsy = ty - cy, bsz = tz - cz;
        const float nb_n = sqrtf(bnx*bnx + bny*bny + bnz*bnz);
        const float nb_s = sqrtf(bsx*bsx + bsy*bsy + bsz*bsz);
        const float f = nb_n / (nb_n + nb_s + EPSF);
        const float vbnx = (ox - tx) * f, vbny = (oy - ty) * f, vbnz = (oz - tz) * f;
        const float g2 = -nb_s / (nb_n + EPSF);
        const float vbsx = vbnx * g2, vbsy = vbny * g2, vbsz = vbnz * g2;
        const float n_n = sqrtf(vbnx*vbnx + vbny*vbny + vbnz*vbnz);
        const float n_s = sqrtf(vbsx*vbsx + vbsy*vbsy + vbsz*vbsz);
        const float trx = ox - vbnx, tr_y = oy - vbny, trz = oz - vbnz;
        const float inn = 1.0f / ((n_n + EPSF) * (n_n + EPSF));
        const float ins = 1.0f / ((n_s + EPSF) * (n_s + EPSF));
        const float gx = vbnx * inn * a_n - vbsx * ins * a_s;
        const float gy = vbny * inn * a_n - vbsy * ins * a_s;
        const float gz = vbnz * inn * a_n - vbsz * ins * a_s;
        const float h = -(trx * gx + tr_y * gy + trz * gz) + be_n - be_s;
        float* gm = geom + (j * 2 + gi) * 12;
        gm[0] = gx; gm[1] = gy; gm[2] = gz; gm[3] = h;
        gm[4] = px; gm[5] = py; gm[6] = pz;
        gm[7] = cx; gm[8] = cy; gm[9] = cz;
        gm[10] = 0.0f; gm[11] = 0.0f;
    }

    {
        const int j = t >> 4, o = t & 15;
        const float* cond = Bcond + j * 288;
        const float* w = cW0 + j * 288 * 16 + o;
        float acc = cb0[j * 16 + o];
        for (int d = 0; d < 288; ++d) acc = fmaf(cond[d], w[d * 16], acc);
        hbuf[j][o] = softplus_fast(acc);
    }
    __syncthreads();
    {
        const int j = t >> 4, o = t & 15;
        const float* w = cW1 + j * 256 + o;
        float acc = cb1[j * 16 + o];
        #pragma unroll
        for (int d = 0; d < 16; ++d) acc = fmaf(hbuf[j][d], w[d * 16], acc);
        acc = softplus_fast(acc);
        __syncthreads();
        hbuf[j][o] = acc;
    }
    __syncthreads();
    if (t < JN * 4) {
        const int j = t >> 2, o = t & 3;
        const float* w = cW2 + j * 64 + o;
        float acc = cb2[j * 4 + o];
        #pragma unroll
        for (int d = 0; d < 16; ++d) acc = fmaf(hbuf[j][d], w[d * 4], acc);
        c4[j * 4 + o] = acc;
    }
}

// ---------------------------------------------------------------------------
// Kernel 2: weight split into doubled-K B-fragment planes.
// Within a plane, idx = ((ks*8 + nt)*64 + lane)*8 + j8 maps to ext slot
// k_ext = ks*32 + (lane>>4)*8 + j8 of output column n = nt*16 + (lane&15).
// ---------------------------------------------------------------------------
__global__ __launch_bounds__(256) void wprep_kernel(
    const float* __restrict__ W0, const float* __restrict__ W1,
    const float* __restrict__ W2, unsigned short* __restrict__ wt)
{
    const int g = blockIdx.x * 256 + threadIdx.x;   // < 24*139264
    const int jj = g / WJ_STRIDE;
    const int r = g - jj * WJ_STRIDE;
    const float* src; int kin, pr; bool loP;
    if (r < 8192)       { src = W0 + jj * 896;   kin = 7;   pr = r & 4095;            loP = r >= L0B; }
    else if (r < 73728) { src = W1 + jj * 16384; kin = 128; pr = (r - L1A) & 32767;   loP = r >= L1B; }
    else                { src = W2 + jj * 16384; kin = 128; pr = (r - L2A) & 32767;   loP = r >= L2B; }
    const int j8   = pr & 7;
    const int lane = (pr >> 3) & 63;
    const int nt   = (pr >> 9) & 7;
    const int ks   = pr >> 12;
    const int n = nt * 16 + (lane & 15);
    const int kext = ks * 32 + (lane >> 4) * 8 + j8;
    const int k = kext >> 1;
    const float v = (k < kin) ? src[k * 128 + n] : 0.0f;
    const unsigned short h = f2bf(v);
    unsigned short outv;
    if (!loP) outv = h;                                        // hi plane: dup to both slots
    else      outv = (kext & 1) ? (unsigned short)0 : f2bf(v - bf2f(h));  // lo plane: [lo,0]
    wt[jj * WJ_STRIDE + r] = outv;
}

// ---------------------------------------------------------------------------
// Kernel 3: main. Doubled-K MFMA: packed hi|lo dwords in LDS ARE the
// A-fragment (ext slots read via one ds_read_b128, zero v_perm).
// ---------------------------------------------------------------------------
__device__ __forceinline__ void mfma_layer(
    unsigned int* __restrict__ X,
    const unsigned short* __restrict__ wA,
    const unsigned short* __restrict__ wB,
    const float* __restrict__ bvec,
    int q, int lane, int nks)
{
    const int l = lane & 15;
    const int quad = lane >> 4;
    const float bia0 = bvec[q * 32 + l];        // ni=0 channel bias (col l)
    const float bia1 = bvec[q * 32 + 16 + l];   // ni=1
    f32x4 acc[4][2];
    #pragma unroll
    for (int mi = 0; mi < 4; ++mi) {
        acc[mi][0] = (f32x4){bia0, bia0, bia0, bia0};
        acc[mi][1] = (f32x4){bia1, bia1, bia1, bia1};
    }

    #pragma unroll 1
    for (int ks = 0; ks < nks; ++ks) {
        bfrag bA[2], bB[2];
        #pragma unroll
        for (int ni = 0; ni < 2; ++ni) {
            const int off = ((ks * 8 + (q * 2 + ni)) * 64 + lane) * 8;
            bA[ni] = *(const bfrag*)(wA + off);   // coalesced 16B/lane
            bB[ni] = *(const bfrag*)(wB + off);
        }
        #pragma unroll
        for (int mi = 0; mi < 4; ++mi) {
            // ext slots ks*32 + quad*8 + [0..7] == dwords ks*16 + quad*4 + [0..3]
            const bfrag a = *(const bfrag*)(
                (const unsigned short*)(X + (mi * 16 + l) * KP) + ks * 32 + quad * 8);
            #pragma unroll
            for (int ni = 0; ni < 2; ++ni) {
                acc[mi][ni] = __builtin_amdgcn_mfma_f32_16x16x32_bf16(a, bA[ni], acc[mi][ni], 0, 0, 0);
                acc[mi][ni] = __builtin_amdgcn_mfma_f32_16x16x32_bf16(a, bB[ni], acc[mi][ni], 0, 0, 0);
            }
        }
    }
    __syncthreads();   // all A reads done before overwrite
    #pragma unroll
    for (int ni = 0; ni < 2; ++ni) {
        const int ch = q * 32 + ni * 16 + l;
        #pragma unroll
        for (int mi = 0; mi < 4; ++mi) {
            #pragma unroll
            for (int r = 0; r < 4; ++r) {
                const float v = softplus_fast(acc[mi][ni][r]);
                const int p = mi * 16 + quad * 4 + r;
                X[p * KP + ch] = pack_hl(v);
            }
        }
    }
    __syncthreads();
}

__global__ __launch_bounds__(256, 4) void main_kernel(
    const float* __restrict__ pts, const float* __restrict__ Btr,
    const float* __restrict__ Brot,
    const float* __restrict__ b0, const float* __restrict__ b1,
    const float* __restrict__ b2, const float* __restrict__ W3,
    const float* __restrict__ b3,
    const float* __restrict__ c4, const float* __restrict__ geom,
    const unsigned short* __restrict__ wt,
    float* __restrict__ pred)
{
    __shared__ unsigned int X[TILE * KP];
    const int j = blockIdx.y;
    const int v0 = blockIdx.x * TILE;
    const int t = threadIdx.x;
    const int lane = t & 63;
    const int q = __builtin_amdgcn_readfirstlane(t >> 6);

    // --- phase 0: local coords + neighbor deformation -> packed input rows ---
    if (t < TILE) {
        const int v = v0 + t;
        float plx = 0.0f, ply = 0.0f, plz = 0.0f;
        if (v < VN) {
            const float dx = pts[v * 3 + 0] - Btr[j * 3 + 0];
            const float dy = pts[v * 3 + 1] - Btr[j * 3 + 1];
            const float dz = pts[v * 3 + 2] - Btr[j * 3 + 2];
            const float* R = Brot + j * 9;
            plx = R[0] * dx + R[3] * dy + R[6] * dz;
            ply = R[1] * dx + R[4] * dy + R[7] * dz;
            plz = R[2] * dx + R[5] * dy + R[8] * dz;
            float osx = 0.0f, osy = 0.0f, osz = 0.0f;
            #pragma unroll
            for (int gi = 0; gi < 2; ++gi) {
                const float* gm = geom + (j * 2 + gi) * 12;
                const float arg = plx * gm[0] + ply * gm[1] + plz * gm[2] + gm[3];
                const float w = 1.0f / (1.0f + __expf(-arg));
                const float aax = -gm[4] * w, aay = -gm[5] * w, aaz = -gm[6] * w;
                const float jcx = gm[7], jcy = gm[8], jcz = gm[9];
                const float ang = sqrtf(aax * aax + aay * aay + aaz * aaz);
                const float inv = ang < 1e-12f ? 1.0f : 1.0f / ang;
                const float ux = aax * inv, uy = aay * inv, uz = aaz * inv;
                const float co = __cosf(ang), si = __sinf(ang), C = 1.0f - co;
                const float vx = plx - jcx, vy = ply - jcy, vz = plz - jcz;
                const float du = ux * vx + uy * vy + uz * vz;
                const float cxv = uy * vz - uz * vy;
                const float cyv = uz * vx - ux * vz;
                const float czv = ux * vy - uy * vx;
                float offx = co * vx + si * cxv + C * ux * du + jcx - plx;
                float offy = co * vy + si * cyv + C * uy * du + jcy - ply;
                float offz = co * vz + si * czv + C * uz * du + jcz - plz;
                if (isnan(offx)) offx = 0.0f;
                if (isnan(offy)) offy = 0.0f;
                if (isnan(offz)) offz = 0.0f;
                osx += offx; osy += offy; osz += offz;
            }
            plx += osx; ply += osy; plz += osz;
        }
        X[t * KP + 0] = pack_hl(plx);
        X[t * KP + 1] = pack_hl(ply);
        X[t * KP + 2] = pack_hl(plz);
        X[t * KP + 3] = pack_hl(c4[j * 4 + 0]);
        X[t * KP + 4] = pack_hl(c4[j * 4 + 1]);
        X[t * KP + 5] = pack_hl(c4[j * 4 + 2]);
        X[t * KP + 6] = pack_hl(c4[j * 4 + 3]);
        // layer-0 A reads touch dwords 0..15 only (ext K=32)
        #pragma unroll
        for (int k = 7; k < 16; ++k) X[t * KP + k] = 0u;
    }
    __syncthreads();

    const unsigned short* wj = wt + j * WJ_STRIDE;
    mfma_layer(X, wj + L0A, wj + L0B, b0 + j * 128, q, lane, 1);
    mfma_layer(X, wj + L1A, wj + L1B, b1 + j * 128, q, lane, 8);
    mfma_layer(X, wj + L2A, wj + L2B, b2 + j * 128, q, lane, 8);

    // --- layer 3: 128 -> 1 (fp32), partials in spare cols 128..131 ---
    {
        const float* w3 = W3 + j * 128 + q * 32;   // wave-uniform
        float part = 0.0f;
        #pragma unroll 8
        for (int kk = 0; kk < 32; ++kk) {
            const unsigned int d = X[lane * KP + q * 32 + kk];
            const float xv = __uint_as_float(d << 16)
                           + __uint_as_float(d & 0xffff0000u);
            part = fmaf(xv, w3[kk], part);
        }
        X[lane * KP + 128 + q] = __float_as_uint(part);
    }
    __syncthreads();
    if (t < TILE) {
        const int v = v0 + t;
        const float r = b3[j]
            + __uint_as_float(X[t * KP + 128]) + __uint_as_float(X[t * KP + 129])
            + __uint_as_float(X[t * KP + 130]) + __uint_as_float(X[t * KP + 131]);
        if (v < VN) pred[j * VN + v] = r;
    }
}

// ---------------------------------------------------------------------------
// Kernel 4: softmin blend over J
// ---------------------------------------------------------------------------
__global__ __launch_bounds__(256) void softmin_kernel(const float* __restrict__ pred,
                                                      float* __restrict__ out)
{
    const int v = blockIdx.x * 256 + threadIdx.x;
    if (v >= VN) return;
    float vals[JN];
    float m = 3.4e38f;
    #pragma unroll
    for (int jj = 0; jj < JN; ++jj) {
        vals[jj] = pred[jj * VN + v];
        m = fminf(m, vals[jj]);
    }
    float s1 = 0.0f, s2 = 0.0f;
    #pragma unroll
    for (int jj = 0; jj < JN; ++jj) {
        const float d = vals[jj] - m;
        const float e = __expf(-200.0f * d);
        s1 += e;
        s2 = fmaf(d, e, s2);
    }
    out[v] = s2 / s1 + m;
}

extern "C" void kernel_launch(void* const* d_in, const int* in_sizes, int n_in,
                              void* d_out, int out_size, void* d_ws, size_t ws_size,
                              hipStream_t stream)
{
    const float* pts    = (const float*)d_in[0];
    const float* Bcond  = (const float*)d_in[1];
    const float* Btr    = (const float*)d_in[2];
    const float* Brot   = (const float*)d_in[3];
    const float* Bneigh = (const float*)d_in[4];
    const float* ralpha = (const float*)d_in[5];
    const float* rbeta  = (const float*)d_in[6];
    const float* cW0 = (const float*)d_in[7];
    const float* cb0 = (const float*)d_in[8];
    const float* cW1 = (const float*)d_in[9];
    const float* cb1 = (const float*)d_in[10];
    const float* cW2 = (const float*)d_in[11];
    const float* cb2 = (const float*)d_in[12];
    const float* W0 = (const float*)d_in[13];
    const float* b0 = (const float*)d_in[14];
    const float* W1 = (const float*)d_in[15];
    const float* b1 = (const float*)d_in[16];
    const float* W2 = (const float*)d_in[17];
    const float* b2 = (const float*)d_in[18];
    const float* W3 = (const float*)d_in[19];
    const float* b3 = (const float*)d_in[20];

    float* ws   = (float*)d_ws;
    float* pred = ws;                           // JN*VN floats
    float* c4   = ws + JN * VN;                 // 96
    float* geom = c4 + JN * 4;                  // 576
    unsigned short* wt = (unsigned short*)(geom + JN * 2 * 12);  // 24*139264 ushorts

    prep_kernel<<<1, 384, 0, stream>>>(Bcond, Bneigh, ralpha, rbeta,
                                       cW0, cb0, cW1, cb1, cW2, cb2, c4, geom);

    wprep_kernel<<<(JN * WJ_STRIDE) / 256, 256, 0, stream>>>(W0, W1, W2, wt);

    dim3 grid((VN + TILE - 1) / TILE, JN);
    main_kernel<<<grid, 256, 0, stream>>>(pts, Btr, Brot,
                                          b0, b1, b2, W3, b3,
                                          c4, geom, wt, pred);

    softmin_kernel<<<(VN + 255) / 256, 256, 0, stream>>>(pred, (float*)d_out);
}

// Round 5
// 262.244 us; speedup vs baseline: 1.0266x; 1.0266x over previous
//
#include <hip/hip_runtime.h>
#include <hip/hip_bf16.h>
#include <math.h>

#define VN 20000
#define JN 24
#define TILE 64
#define KP 132            // packed-activation row pitch in dwords (round-1 proven)
#define EPSF 1e-8f

typedef __attribute__((ext_vector_type(8))) short bfrag;   // 8 bf16 = 4 VGPRs
typedef __attribute__((ext_vector_type(4))) float f32x4;

// per-joint bf16 weight-plane offsets (ushort units) — doubled-K layout.
// ext slot k_ext = 2*k + {0:hi,1:lo} of the activation. Per layer, TWO B planes:
//   plane A: B[2k]=B[2k+1]=w_hi[k]   -> (ah+al)*bh
//   plane B: B[2k]=w_lo[k], B[2k+1]=0 -> ah*bl
#define WJ_STRIDE 139264
#define L0A 0
#define L0B 4096
#define L1A 8192
#define L1B 40960
#define L2A 73728
#define L2B 106496

__device__ __forceinline__ unsigned short f2bf(float x) {
    __hip_bfloat16 b = __float2bfloat16(x);
    unsigned short u; __builtin_memcpy(&u, &b, 2); return u;
}
__device__ __forceinline__ float bf2f(unsigned short u) {
    __hip_bfloat16 b; __builtin_memcpy(&b, &u, 2);
    return __bfloat162float(b);
}
// pack hi|lo bf16 into one dword: low16 = bf16(x) (half-up hi), high16 = bf16(x-hi)
__device__ __forceinline__ unsigned int pack_hl(float x) {
    const unsigned int h = (__float_as_uint(x) + 0x8000u) & 0xffff0000u;
    const float hf = __uint_as_float(h);
    const float lo = x - hf;
    unsigned int r;
    asm("v_cvt_pk_bf16_f32 %0, %1, %2" : "=v"(r) : "v"(hf), "v"(lo));
    return r;
}

// softplus(100x)/100 with ONE transcendental (validated poly, 9 VALU ops)
__device__ __forceinline__ float softplus_fast(float x) {
    const float u = __builtin_amdgcn_exp2f(-144.269504f * fabsf(x));
    float p = fmaf(u, 3.04480e-4f, -1.31584e-3f);
    p = fmaf(u, p, 2.852768e-3f);
    p = fmaf(u, p, -4.902308e-3f);
    p = fmaf(u, p, 9.992342e-3f);
    p = fmaf(u, p, 8.0e-8f);
    return fmaxf(x, 0.0f) + p;
}

// ---------------------------------------------------------------------------
// Kernel 1: per-joint prep (round-1 verbatim, 384 threads)
// ---------------------------------------------------------------------------
__global__ __launch_bounds__(384) void prep_kernel(
    const float* __restrict__ Bcond, const float* __restrict__ Bneigh,
    const float* __restrict__ ralpha, const float* __restrict__ rbeta,
    const float* __restrict__ cW0, const float* __restrict__ cb0,
    const float* __restrict__ cW1, const float* __restrict__ cb1,
    const float* __restrict__ cW2, const float* __restrict__ cb2,
    float* __restrict__ c4, float* __restrict__ geom)
{
    __shared__ float hbuf[JN][16];
    const int t = threadIdx.x;

    if (t < JN * 2) {
        const int j = t >> 1, gi = t & 1;
        const float* nb = Bneigh + (j * 2 + gi) * 15;
        const float tx = nb[0],  ty = nb[1],  tz = nb[2];
        const float cx = nb[3],  cy = nb[4],  cz = nb[5];
        const float ox = nb[6],  oy = nb[7],  oz = nb[8];
        const float px = nb[9],  py = nb[10], pz = nb[11];
        const int bid_this  = (int)nb[12];
        const int bid_other = (int)nb[13];
        const float xa_n = ralpha[bid_other * JN + bid_this] - 1.0f;
        const float xa_s = ralpha[bid_this * JN + bid_other] - 1.0f;
        const float a_n = xa_n > 0.0f ? xa_n + 1.0f : expf(xa_n);
        const float a_s = xa_s > 0.0f ? xa_s + 1.0f : expf(xa_s);
        const float be_n = rbeta[bid_other * JN + bid_this];
        const float be_s = rbeta[bid_this * JN + bid_other];

        const float bnx = ox - cx, bny = oy - cy, bnz = oz - cz;
        const float bsx = tx - cx, bsy = ty - cy, bsz = tz - cz;
        const float nb_n = sqrtf(bnx*bnx + bny*bny + bnz*bnz);
        const float nb_s = sqrtf(bsx*bsx + bsy*bsy + bsz*bsz);
        const float f = nb_n / (nb_n + nb_s + EPSF);
        const float vbnx = (ox - tx) * f, vbny = (oy - ty) * f, vbnz = (oz - tz) * f;
        const float g2 = -nb_s / (nb_n + EPSF);
        const float vbsx = vbnx * g2, vbsy = vbny * g2, vbsz = vbnz * g2;
        const float n_n = sqrtf(vbnx*vbnx + vbny*vbny + vbnz*vbnz);
        const float n_s = sqrtf(vbsx*vbsx + vbsy*vbsy + vbsz*vbsz);
        const float trx = ox - vbnx, tr_y = oy - vbny, trz = oz - vbnz;
        const float inn = 1.0f / ((n_n + EPSF) * (n_n + EPSF));
        const float ins = 1.0f / ((n_s + EPSF) * (n_s + EPSF));
        const float gx = vbnx * inn * a_n - vbsx * ins * a_s;
        const float gy = vbny * inn * a_n - vbsy * ins * a_s;
        const float gz = vbnz * inn * a_n - vbsz * ins * a_s;
        const float h = -(trx * gx + tr_y * gy + trz * gz) + be_n - be_s;
        float* gm = geom + (j * 2 + gi) * 12;
        gm[0] = gx; gm[1] = gy; gm[2] = gz; gm[3] = h;
        gm[4] = px; gm[5] = py; gm[6] = pz;
        gm[7] = cx; gm[8] = cy; gm[9] = cz;
        gm[10] = 0.0f; gm[11] = 0.0f;
    }

    {
        const int j = t >> 4, o = t & 15;
        const float* cond = Bcond + j * 288;
        const float* w = cW0 + j * 288 * 16 + o;
        float acc = cb0[j * 16 + o];
        for (int d = 0; d < 288; ++d) acc = fmaf(cond[d], w[d * 16], acc);
        hbuf[j][o] = softplus_fast(acc);
    }
    __syncthreads();
    {
        const int j = t >> 4, o = t & 15;
        const float* w = cW1 + j * 256 + o;
        float acc = cb1[j * 16 + o];
        #pragma unroll
        for (int d = 0; d < 16; ++d) acc = fmaf(hbuf[j][d], w[d * 16], acc);
        acc = softplus_fast(acc);
        __syncthreads();
        hbuf[j][o] = acc;
    }
    __syncthreads();
    if (t < JN * 4) {
        const int j = t >> 2, o = t & 3;
        const float* w = cW2 + j * 64 + o;
        float acc = cb2[j * 4 + o];
        #pragma unroll
        for (int d = 0; d < 16; ++d) acc = fmaf(hbuf[j][d], w[d * 4], acc);
        c4[j * 4 + o] = acc;
    }
}

// ---------------------------------------------------------------------------
// Kernel 2: weight split into doubled-K B planes — 8 ushorts (16B) per thread.
// Verified element-wise against the scalar round-1 version: plane boundaries
// (4096/8192/40960/73728/106496) are all multiples of 8, so an 8-run never
// crosses planes; j8 = m; even kext -> {hi|lo}, odd kext -> {hi|0}.
// ---------------------------------------------------------------------------
__global__ __launch_bounds__(256) void wprep_kernel(
    const float* __restrict__ W0, const float* __restrict__ W1,
    const float* __restrict__ W2, unsigned short* __restrict__ wt)
{
    const int g = blockIdx.x * 256 + threadIdx.x;      // < 24*17408
    const int jj = g / 17408;
    const int r = (g - jj * 17408) * 8;                // ushort base within joint
    const float* src; int kin, pr; bool loP;
    if (r < 8192)       { src = W0 + jj * 896;   kin = 7;   pr = r & 4095;          loP = r >= L0B; }
    else if (r < 73728) { src = W1 + jj * 16384; kin = 128; pr = (r - L1A) & 32767; loP = r >= L1B; }
    else                { src = W2 + jj * 16384; kin = 128; pr = (r - L2A) & 32767; loP = r >= L2B; }
    const int lane = (pr >> 3) & 63;
    const int nt   = (pr >> 9) & 7;
    const int ks   = pr >> 12;
    const int n  = nt * 16 + (lane & 15);
    const int k0 = (ks * 32 + (lane >> 4) * 8) >> 1;   // even base / 2
    unsigned short out[8];
    #pragma unroll
    for (int kk = 0; kk < 4; ++kk) {
        const float v = (k0 + kk < kin) ? src[(k0 + kk) * 128 + n] : 0.0f;
        const unsigned short h = f2bf(v);
        if (!loP) { out[2*kk] = h; out[2*kk+1] = h; }
        else      { out[2*kk] = f2bf(v - bf2f(h)); out[2*kk+1] = 0; }
    }
    *(uint4*)(wt + jj * WJ_STRIDE + r) = *(const uint4*)out;
}

// ---------------------------------------------------------------------------
// Kernel 3: main — round-1 VERBATIM layout (KP=132, no swizzle, partials in
// spare cols 128..131). Only change: ks loop unroll 1 -> 2 (pure unroll,
// lets the compiler overlap ks+1 B-loads with ks MFMAs).
// ---------------------------------------------------------------------------
template<int NKS>
__device__ __forceinline__ void mfma_layer(
    unsigned int* __restrict__ X,
    const unsigned short* __restrict__ wA,
    const unsigned short* __restrict__ wB,
    const float* __restrict__ bvec,
    int q, int lane)
{
    const int l = lane & 15;
    const int quad = lane >> 4;
    const float bia0 = bvec[q * 32 + l];        // ni=0 channel bias (col l)
    const float bia1 = bvec[q * 32 + 16 + l];   // ni=1
    f32x4 acc[4][2];
    #pragma unroll
    for (int mi = 0; mi < 4; ++mi) {
        acc[mi][0] = (f32x4){bia0, bia0, bia0, bia0};
        acc[mi][1] = (f32x4){bia1, bia1, bia1, bia1};
    }

    #pragma unroll 2
    for (int ks = 0; ks < NKS; ++ks) {
        bfrag bA[2], bB[2];
        #pragma unroll
        for (int ni = 0; ni < 2; ++ni) {
            const int off = ((ks * 8 + (q * 2 + ni)) * 64 + lane) * 8;
            bA[ni] = *(const bfrag*)(wA + off);   // coalesced 16B/lane
            bB[ni] = *(const bfrag*)(wB + off);
        }
        #pragma unroll
        for (int mi = 0; mi < 4; ++mi) {
            // ext slots ks*32 + quad*8 + [0..7] == dwords ks*16 + quad*4 + [0..3]
            const bfrag a = *(const bfrag*)(
                (const unsigned short*)(X + (mi * 16 + l) * KP) + ks * 32 + quad * 8);
            #pragma unroll
            for (int ni = 0; ni < 2; ++ni) {
                acc[mi][ni] = __builtin_amdgcn_mfma_f32_16x16x32_bf16(a, bA[ni], acc[mi][ni], 0, 0, 0);
                acc[mi][ni] = __builtin_amdgcn_mfma_f32_16x16x32_bf16(a, bB[ni], acc[mi][ni], 0, 0, 0);
            }
        }
    }
    __syncthreads();   // all A reads done before overwrite
    #pragma unroll
    for (int ni = 0; ni < 2; ++ni) {
        const int ch = q * 32 + ni * 16 + l;
        #pragma unroll
        for (int mi = 0; mi < 4; ++mi) {
            #pragma unroll
            for (int r = 0; r < 4; ++r) {
                const float v = softplus_fast(acc[mi][ni][r]);
                const int p = mi * 16 + quad * 4 + r;
                X[p * KP + ch] = pack_hl(v);
            }
        }
    }
    __syncthreads();
}

__global__ __launch_bounds__(256, 4) void main_kernel(
    const float* __restrict__ pts, const float* __restrict__ Btr,
    const float* __restrict__ Brot,
    const float* __restrict__ b0, const float* __restrict__ b1,
    const float* __restrict__ b2, const float* __restrict__ W3,
    const float* __restrict__ b3,
    const float* __restrict__ c4, const float* __restrict__ geom,
    const unsigned short* __restrict__ wt,
    float* __restrict__ pred)
{
    __shared__ unsigned int X[TILE * KP];
    const int j = blockIdx.y;
    const int v0 = blockIdx.x * TILE;
    const int t = threadIdx.x;
    const int lane = t & 63;
    const int q = __builtin_amdgcn_readfirstlane(t >> 6);

    // --- phase 0: local coords + neighbor deformation -> packed input rows ---
    if (t < TILE) {
        const int v = v0 + t;
        float plx = 0.0f, ply = 0.0f, plz = 0.0f;
        if (v < VN) {
            const float dx = pts[v * 3 + 0] - Btr[j * 3 + 0];
            const float dy = pts[v * 3 + 1] - Btr[j * 3 + 1];
            const float dz = pts[v * 3 + 2] - Btr[j * 3 + 2];
            const float* R = Brot + j * 9;
            plx = R[0] * dx + R[3] * dy + R[6] * dz;
            ply = R[1] * dx + R[4] * dy + R[7] * dz;
            plz = R[2] * dx + R[5] * dy + R[8] * dz;
            float osx = 0.0f, osy = 0.0f, osz = 0.0f;
            #pragma unroll
            for (int gi = 0; gi < 2; ++gi) {
                const float* gm = geom + (j * 2 + gi) * 12;
                const float arg = plx * gm[0] + ply * gm[1] + plz * gm[2] + gm[3];
                const float w = 1.0f / (1.0f + __expf(-arg));
                const float aax = -gm[4] * w, aay = -gm[5] * w, aaz = -gm[6] * w;
                const float jcx = gm[7], jcy = gm[8], jcz = gm[9];
                const float ang = sqrtf(aax * aax + aay * aay + aaz * aaz);
                const float inv = ang < 1e-12f ? 1.0f : 1.0f / ang;
                const float ux = aax * inv, uy = aay * inv, uz = aaz * inv;
                const float co = __cosf(ang), si = __sinf(ang), C = 1.0f - co;
                const float vx = plx - jcx, vy = ply - jcy, vz = plz - jcz;
                const float du = ux * vx + uy * vy + uz * vz;
                const float cxv = uy * vz - uz * vy;
                const float cyv = uz * vx - ux * vz;
                const float czv = ux * vy - uy * vx;
                float offx = co * vx + si * cxv + C * ux * du + jcx - plx;
                float offy = co * vy + si * cyv + C * uy * du + jcy - ply;
                float offz = co * vz + si * czv + C * uz * du + jcz - plz;
                if (isnan(offx)) offx = 0.0f;
                if (isnan(offy)) offy = 0.0f;
                if (isnan(offz)) offz = 0.0f;
                osx += offx; osy += offy; osz += offz;
            }
            plx += osx; ply += osy; plz += osz;
        }
        X[t * KP + 0] = pack_hl(plx);
        X[t * KP + 1] = pack_hl(ply);
        X[t * KP + 2] = pack_hl(plz);
        X[t * KP + 3] = pack_hl(c4[j * 4 + 0]);
        X[t * KP + 4] = pack_hl(c4[j * 4 + 1]);
        X[t * KP + 5] = pack_hl(c4[j * 4 + 2]);
        X[t * KP + 6] = pack_hl(c4[j * 4 + 3]);
        // layer-0 A reads touch dwords 0..15 only (ext K=32)
        #pragma unroll
        for (int k = 7; k < 16; ++k) X[t * KP + k] = 0u;
    }
    __syncthreads();

    const unsigned short* wj = wt + j * WJ_STRIDE;
    mfma_layer<1>(X, wj + L0A, wj + L0B, b0 + j * 128, q, lane);
    mfma_layer<8>(X, wj + L1A, wj + L1B, b1 + j * 128, q, lane);
    mfma_layer<8>(X, wj + L2A, wj + L2B, b2 + j * 128, q, lane);

    // --- layer 3: 128 -> 1 (fp32), partials in spare cols 128..131 ---
    {
        const float* w3 = W3 + j * 128 + q * 32;   // wave-uniform
        float part = 0.0f;
        #pragma unroll 8
        for (int kk = 0; kk < 32; ++kk) {
            const unsigned int d = X[lane * KP + q * 32 + kk];
            const float xv = __uint_as_float(d << 16)
                           + __uint_as_float(d & 0xffff0000u);
            part = fmaf(xv, w3[kk], part);
        }
        X[lane * KP + 128 + q] = __float_as_uint(part);
    }
    __syncthreads();
    if (t < TILE) {
        const int v = v0 + t;
        const float r = b3[j]
            + __uint_as_float(X[t * KP + 128]) + __uint_as_float(X[t * KP + 129])
            + __uint_as_float(X[t * KP + 130]) + __uint_as_float(X[t * KP + 131]);
        if (v < VN) pred[j * VN + v] = r;
    }
}

// ---------------------------------------------------------------------------
// Kernel 4: softmin blend over J
// ---------------------------------------------------------------------------
__global__ __launch_bounds__(256) void softmin_kernel(const float* __restrict__ pred,
                                                      float* __restrict__ out)
{
    const int v = blockIdx.x * 256 + threadIdx.x;
    if (v >= VN) return;
    float vals[JN];
    float m = 3.4e38f;
    #pragma unroll
    for (int jj = 0; jj < JN; ++jj) {
        vals[jj] = pred[jj * VN + v];
        m = fminf(m, vals[jj]);
    }
    float s1 = 0.0f, s2 = 0.0f;
    #pragma unroll
    for (int jj = 0; jj < JN; ++jj) {
        const float d = vals[jj] - m;
        const float e = __expf(-200.0f * d);
        s1 += e;
        s2 = fmaf(d, e, s2);
    }
    out[v] = s2 / s1 + m;
}

extern "C" void kernel_launch(void* const* d_in, const int* in_sizes, int n_in,
                              void* d_out, int out_size, void* d_ws, size_t ws_size,
                              hipStream_t stream)
{
    const float* pts    = (const float*)d_in[0];
    const float* Bcond  = (const float*)d_in[1];
    const float* Btr    = (const float*)d_in[2];
    const float* Brot   = (const float*)d_in[3];
    const float* Bneigh = (const float*)d_in[4];
    const float* ralpha = (const float*)d_in[5];
    const float* rbeta  = (const float*)d_in[6];
    const float* cW0 = (const float*)d_in[7];
    const float* cb0 = (const float*)d_in[8];
    const float* cW1 = (const float*)d_in[9];
    const float* cb1 = (const float*)d_in[10];
    const float* cW2 = (const float*)d_in[11];
    const float* cb2 = (const float*)d_in[12];
    const float* W0 = (const float*)d_in[13];
    const float* b0 = (const float*)d_in[14];
    const float* W1 = (const float*)d_in[15];
    const float* b1 = (const float*)d_in[16];
    const float* W2 = (const float*)d_in[17];
    const float* b2 = (const float*)d_in[18];
    const float* W3 = (const float*)d_in[19];
    const float* b3 = (const float*)d_in[20];

    float* ws   = (float*)d_ws;
    float* pred = ws;                           // JN*VN floats
    float* c4   = ws + JN * VN;                 // 96
    float* geom = c4 + JN * 4;                  // 576
    unsigned short* wt = (unsigned short*)(geom + JN * 2 * 12);  // 24*139264 ushorts

    prep_kernel<<<1, 384, 0, stream>>>(Bcond, Bneigh, ralpha, rbeta,
                                       cW0, cb0, cW1, cb1, cW2, cb2, c4, geom);

    wprep_kernel<<<(JN * 17408) / 256, 256, 0, stream>>>(W0, W1, W2, wt);

    dim3 grid((VN + TILE - 1) / TILE, JN);
    main_kernel<<<grid, 256, 0, stream>>>(pts, Btr, Brot,
                                          b0, b1, b2, W3, b3,
                                          c4, geom, wt, pred);

    softmin_kernel<<<(VN + 255) / 256, 256, 0, stream>>>(pred, (float*)d_out);
}

// Round 7
// 257.797 us; speedup vs baseline: 1.0443x; 1.0173x over previous
//
#include <hip/hip_runtime.h>
#include <hip/hip_bf16.h>
#include <math.h>

#define VN 20000
#define JN 24
#define TILE 64
#define KP 132            // packed-activation row pitch in dwords (round-1 proven)
#define EPSF 1e-8f
#define NXB 313           // blocks along V
#define WPREP_BLOCKS 1632 // (JN*17408)/256

typedef __attribute__((ext_vector_type(8))) short bfrag;   // 8 bf16 = 4 VGPRs
typedef __attribute__((ext_vector_type(4))) float f32x4;

// per-joint bf16 weight-plane offsets (ushort units) — doubled-K layout (r5).
// ext slot k_ext = 2*k + {0:hi,1:lo} of the activation. Per layer, TWO B planes:
//   plane A: B[2k]=B[2k+1]=w_hi[k]   -> (ah+al)*bh
//   plane B: B[2k]=w_lo[k], B[2k+1]=0 -> ah*bl
#define WJ_STRIDE 139264
#define L0A 0
#define L0B 4096
#define L1A 8192
#define L1B 40960
#define L2A 73728
#define L2B 106496

__device__ __forceinline__ unsigned short f2bf(float x) {
    __hip_bfloat16 b = __float2bfloat16(x);
    unsigned short u; __builtin_memcpy(&u, &b, 2); return u;
}
__device__ __forceinline__ float bf2f(unsigned short u) {
    __hip_bfloat16 b; __builtin_memcpy(&b, &u, 2);
    return __bfloat162float(b);
}
// pack hi|lo bf16 into one dword: low16 = bf16(x) (half-up hi), high16 = bf16(x-hi)
__device__ __forceinline__ unsigned int pack_hl(float x) {
    const unsigned int h = (__float_as_uint(x) + 0x8000u) & 0xffff0000u;
    const float hf = __uint_as_float(h);
    const float lo = x - hf;
    unsigned int r;
    asm("v_cvt_pk_bf16_f32 %0, %1, %2" : "=v"(r) : "v"(hf), "v"(lo));
    return r;
}

// softplus(100x)/100 with ONE transcendental (validated poly, 9 VALU ops)
__device__ __forceinline__ float softplus_fast(float x) {
    const float u = __builtin_amdgcn_exp2f(-144.269504f * fabsf(x));
    float p = fmaf(u, 3.04480e-4f, -1.31584e-3f);
    p = fmaf(u, p, 2.852768e-3f);
    p = fmaf(u, p, -4.902308e-3f);
    p = fmaf(u, p, 9.992342e-3f);
    p = fmaf(u, p, 8.0e-8f);
    return fmaxf(x, 0.0f) + p;
}

// ---------------------------------------------------------------------------
// Kernel 1 (fused setup): blocks [0, WPREP_BLOCKS) = r5's vectorized weight
// split (verbatim); blocks [WPREP_BLOCKS, +JN) = per-joint prep, parallelized
// (one block per joint; 288-dot split into 16 chunks x 16 outputs).
// prep was previously a single block — its serial-load latency ran naked on
// one CU; now it rides concurrently with wprep.
// ---------------------------------------------------------------------------
__global__ __launch_bounds__(256) void setup_kernel(
    const float* __restrict__ W0, const float* __restrict__ W1,
    const float* __restrict__ W2, unsigned short* __restrict__ wt,
    const float* __restrict__ Bcond, const float* __restrict__ Bneigh,
    const float* __restrict__ ralpha, const float* __restrict__ rbeta,
    const float* __restrict__ cW0, const float* __restrict__ cb0,
    const float* __restrict__ cW1, const float* __restrict__ cb1,
    const float* __restrict__ cW2, const float* __restrict__ cb2,
    float* __restrict__ c4, float* __restrict__ geom)
{
    if (blockIdx.x < WPREP_BLOCKS) {
        // ---- wprep (r5 verbatim): 8 ushorts (16B) per thread ----
        const int g = blockIdx.x * 256 + threadIdx.x;      // < 24*17408
        const int jj = g / 17408;
        const int r = (g - jj * 17408) * 8;                // ushort base within joint
        const float* src; int kin, pr; bool loP;
        if (r < 8192)       { src = W0 + jj * 896;   kin = 7;   pr = r & 4095;          loP = r >= L0B; }
        else if (r < 73728) { src = W1 + jj * 16384; kin = 128; pr = (r - L1A) & 32767; loP = r >= L1B; }
        else                { src = W2 + jj * 16384; kin = 128; pr = (r - L2A) & 32767; loP = r >= L2B; }
        const int lane = (pr >> 3) & 63;
        const int nt   = (pr >> 9) & 7;
        const int ks   = pr >> 12;
        const int n  = nt * 16 + (lane & 15);
        const int k0 = (ks * 32 + (lane >> 4) * 8) >> 1;   // even base / 2
        unsigned short out[8];
        #pragma unroll
        for (int kk = 0; kk < 4; ++kk) {
            const float v = (k0 + kk < kin) ? src[(k0 + kk) * 128 + n] : 0.0f;
            const unsigned short h = f2bf(v);
            if (!loP) { out[2*kk] = h; out[2*kk+1] = h; }
            else      { out[2*kk] = f2bf(v - bf2f(h)); out[2*kk+1] = 0; }
        }
        *(uint4*)(wt + jj * WJ_STRIDE + r) = *(const uint4*)out;
        return;
    }

    // ---- prep: one block per joint ----
    __shared__ float cond_s[288];
    __shared__ float sh[16][17];
    __shared__ float hb[16];
    const int j = blockIdx.x - WPREP_BLOCKS;   // 0..23
    const int t = threadIdx.x;

    for (int i = t; i < 288; i += 256) cond_s[i] = Bcond[j * 288 + i];

    if (t < 2) {
        const int gi = t;
        const float* nb = Bneigh + (j * 2 + gi) * 15;
        const float tx = nb[0],  ty = nb[1],  tz = nb[2];
        const float cx = nb[3],  cy = nb[4],  cz = nb[5];
        const float ox = nb[6],  oy = nb[7],  oz = nb[8];
        const float px = nb[9],  py = nb[10], pz = nb[11];
        const int bid_this  = (int)nb[12];
        const int bid_other = (int)nb[13];
        const float xa_n = ralpha[bid_other * JN + bid_this] - 1.0f;
        const float xa_s = ralpha[bid_this * JN + bid_other] - 1.0f;
        const float a_n = xa_n > 0.0f ? xa_n + 1.0f : expf(xa_n);
        const float a_s = xa_s > 0.0f ? xa_s + 1.0f : expf(xa_s);
        const float be_n = rbeta[bid_other * JN + bid_this];
        const float be_s = rbeta[bid_this * JN + bid_other];

        const float bnx = ox - cx, bny = oy - cy, bnz = oz - cz;
        const float bsx = tx - cx, bsy = ty - cy, bsz = tz - cz;
        const float nb_n = sqrtf(bnx*bnx + bny*bny + bnz*bnz);
        const float nb_s = sqrtf(bsx*bsx + bsy*bsy + bsz*bsz);
        const float f = nb_n / (nb_n + nb_s + EPSF);
        const float vbnx = (ox - tx) * f, vbny = (oy - ty) * f, vbnz = (oz - tz) * f;
        const float g2 = -nb_s / (nb_n + EPSF);
        const float vbsx = vbnx * g2, vbsy = vbny * g2, vbsz = vbnz * g2;
        const float n_n = sqrtf(vbnx*vbnx + vbny*vbny + vbnz*vbnz);
        const float n_s = sqrtf(vbsx*vbsx + vbsy*vbsy + vbsz*vbsz);
        const float trx = ox - vbnx, tr_y = oy - vbny, trz = oz - vbnz;
        const float inn = 1.0f / ((n_n + EPSF) * (n_n + EPSF));
        const float ins = 1.0f / ((n_s + EPSF) * (n_s + EPSF));
        const float gx = vbnx * inn * a_n - vbsx * ins * a_s;
        const float gy = vbny * inn * a_n - vbsy * ins * a_s;
        const float gz = vbnz * inn * a_n - vbsz * ins * a_s;
        const float h = -(trx * gx + tr_y * gy + trz * gz) + be_n - be_s;
        float* gm = geom + (j * 2 + gi) * 12;
        gm[0] = gx; gm[1] = gy; gm[2] = gz; gm[3] = h;
        gm[4] = px; gm[5] = py; gm[6] = pz;
        gm[7] = cx; gm[8] = cy; gm[9] = cz;
        gm[10] = 0.0f; gm[11] = 0.0f;
    }
    __syncthreads();

    // cMLP L0: 16 outputs x 16 chunks of 18
    {
        const int o = t & 15, c = t >> 4;
        const float* w = cW0 + j * 288 * 16 + o;
        const int d0 = c * 18;
        float acc = 0.0f;
        #pragma unroll
        for (int d = 0; d < 18; ++d) acc = fmaf(cond_s[d0 + d], w[(d0 + d) * 16], acc);
        sh[c][o] = acc;
    }
    __syncthreads();
    if (t < 16) {
        float acc = cb0[j * 16 + t];
        #pragma unroll
        for (int c = 0; c < 16; ++c) acc += sh[c][t];
        hb[t] = softplus_fast(acc);
    }
    __syncthreads();
    if (t < 16) {
        const float* w = cW1 + j * 256 + t;
        float acc = cb1[j * 16 + t];
        #pragma unroll
        for (int d = 0; d < 16; ++d) acc = fmaf(hb[d], w[d * 16], acc);
        sh[0][t] = softplus_fast(acc);
    }
    __syncthreads();
    if (t < 4) {
        const float* w = cW2 + j * 64 + t;
        float acc = cb2[j * 4 + t];
        #pragma unroll
        for (int d = 0; d < 16; ++d) acc = fmaf(sh[0][d], w[d * 4], acc);
        c4[j * 4 + t] = acc;
    }
}

// ---------------------------------------------------------------------------
// Kernel 2: main — r5 verbatim except 1D grid + XCD-aware (j,x) decode.
// 7512 blocks = 8 XCDs x (3 j x 313 x): xcd = bid&7 holds j in {3*xcd..3*xcd+2}
// -> per-XCD weight working set 3 x 278KB = 840KB, fits 4MiB L2 (was 6.7MB).
// ---------------------------------------------------------------------------
template<int NKS>
__device__ __forceinline__ void mfma_layer(
    unsigned int* __restrict__ X,
    const unsigned short* __restrict__ wA,
    const unsigned short* __restrict__ wB,
    const float* __restrict__ bvec,
    int q, int lane)
{
    const int l = lane & 15;
    const int quad = lane >> 4;
    const float bia0 = bvec[q * 32 + l];        // ni=0 channel bias (col l)
    const float bia1 = bvec[q * 32 + 16 + l];   // ni=1
    f32x4 acc[4][2];
    #pragma unroll
    for (int mi = 0; mi < 4; ++mi) {
        acc[mi][0] = (f32x4){bia0, bia0, bia0, bia0};
        acc[mi][1] = (f32x4){bia1, bia1, bia1, bia1};
    }

    #pragma unroll 2
    for (int ks = 0; ks < NKS; ++ks) {
        bfrag bA[2], bB[2];
        #pragma unroll
        for (int ni = 0; ni < 2; ++ni) {
            const int off = ((ks * 8 + (q * 2 + ni)) * 64 + lane) * 8;
            bA[ni] = *(const bfrag*)(wA + off);   // coalesced 16B/lane
            bB[ni] = *(const bfrag*)(wB + off);
        }
        #pragma unroll
        for (int mi = 0; mi < 4; ++mi) {
            // ext slots ks*32 + quad*8 + [0..7] == dwords ks*16 + quad*4 + [0..3]
            const bfrag a = *(const bfrag*)(
                (const unsigned short*)(X + (mi * 16 + l) * KP) + ks * 32 + quad * 8);
            #pragma unroll
            for (int ni = 0; ni < 2; ++ni) {
                acc[mi][ni] = __builtin_amdgcn_mfma_f32_16x16x32_bf16(a, bA[ni], acc[mi][ni], 0, 0, 0);
                acc[mi][ni] = __builtin_amdgcn_mfma_f32_16x16x32_bf16(a, bB[ni], acc[mi][ni], 0, 0, 0);
            }
        }
    }
    __syncthreads();   // all A reads done before overwrite
    #pragma unroll
    for (int ni = 0; ni < 2; ++ni) {
        const int ch = q * 32 + ni * 16 + l;
        #pragma unroll
        for (int mi = 0; mi < 4; ++mi) {
            #pragma unroll
            for (int r = 0; r < 4; ++r) {
                const float v = softplus_fast(acc[mi][ni][r]);
                const int p = mi * 16 + quad * 4 + r;
                X[p * KP + ch] = pack_hl(v);
            }
        }
    }
    __syncthreads();
}

__global__ __launch_bounds__(256, 4) void main_kernel(
    const float* __restrict__ pts, const float* __restrict__ Btr,
    const float* __restrict__ Brot,
    const float* __restrict__ b0, const float* __restrict__ b1,
    const float* __restrict__ b2, const float* __restrict__ W3,
    const float* __restrict__ b3,
    const float* __restrict__ c4, const float* __restrict__ geom,
    const unsigned short* __restrict__ wt,
    float* __restrict__ pred)
{
    __shared__ unsigned int X[TILE * KP];
    // XCD-aware decode: bid = xcd + 8*(x*3 + jloc), j = xcd*3 + jloc
    const int bid = blockIdx.x;
    const int xcd = bid & 7;
    const int s = bid >> 3;          // 0..938
    const int j = xcd * 3 + (s % 3);
    const int v0 = (s / 3) * TILE;
    const int t = threadIdx.x;
    const int lane = t & 63;
    const int q = __builtin_amdgcn_readfirstlane(t >> 6);

    // --- phase 0: local coords + neighbor deformation -> packed input rows ---
    if (t < TILE) {
        const int v = v0 + t;
        float plx = 0.0f, ply = 0.0f, plz = 0.0f;
        if (v < VN) {
            const float dx = pts[v * 3 + 0] - Btr[j * 3 + 0];
            const float dy = pts[v * 3 + 1] - Btr[j * 3 + 1];
            const float dz = pts[v * 3 + 2] - Btr[j * 3 + 2];
            const float* R = Brot + j * 9;
            plx = R[0] * dx + R[3] * dy + R[6] * dz;
            ply = R[1] * dx + R[4] * dy + R[7] * dz;
            plz = R[2] * dx + R[5] * dy + R[8] * dz;
            float osx = 0.0f, osy = 0.0f, osz = 0.0f;
            #pragma unroll
            for (int gi = 0; gi < 2; ++gi) {
                const float* gm = geom + (j * 2 + gi) * 12;
                const float arg = plx * gm[0] + ply * gm[1] + plz * gm[2] + gm[3];
                const float w = 1.0f / (1.0f + __expf(-arg));
                const float aax = -gm[4] * w, aay = -gm[5] * w, aaz = -gm[6] * w;
                const float jcx = gm[7], jcy = gm[8], jcz = gm[9];
                const float ang = sqrtf(aax * aax + aay * aay + aaz * aaz);
                const float inv = ang < 1e-12f ? 1.0f : 1.0f / ang;
                const float ux = aax * inv, uy = aay * inv, uz = aaz * inv;
                const float co = __cosf(ang), si = __sinf(ang), C = 1.0f - co;
                const float vx = plx - jcx, vy = ply - jcy, vz = plz - jcz;
                const float du = ux * vx + uy * vy + uz * vz;
                const float cxv = uy * vz - uz * vy;
                const float cyv = uz * vx - ux * vz;
                const float czv = ux * vy - uy * vx;
                float offx = co * vx + si * cxv + C * ux * du + jcx - plx;
                float offy = co * vy + si * cyv + C * uy * du + jcy - ply;
                float offz = co * vz + si * czv + C * uz * du + jcz - plz;
                if (isnan(offx)) offx = 0.0f;
                if (isnan(offy)) offy = 0.0f;
                if (isnan(offz)) offz = 0.0f;
                osx += offx; osy += offy; osz += offz;
            }
            plx += osx; ply += osy; plz += osz;
        }
        X[t * KP + 0] = pack_hl(plx);
        X[t * KP + 1] = pack_hl(ply);
        X[t * KP + 2] = pack_hl(plz);
        X[t * KP + 3] = pack_hl(c4[j * 4 + 0]);
        X[t * KP + 4] = pack_hl(c4[j * 4 + 1]);
        X[t * KP + 5] = pack_hl(c4[j * 4 + 2]);
        X[t * KP + 6] = pack_hl(c4[j * 4 + 3]);
        // layer-0 A reads touch dwords 0..15 only (ext K=32)
        #pragma unroll
        for (int k = 7; k < 16; ++k) X[t * KP + k] = 0u;
    }
    __syncthreads();

    const unsigned short* wj = wt + j * WJ_STRIDE;
    mfma_layer<1>(X, wj + L0A, wj + L0B, b0 + j * 128, q, lane);
    mfma_layer<8>(X, wj + L1A, wj + L1B, b1 + j * 128, q, lane);
    mfma_layer<8>(X, wj + L2A, wj + L2B, b2 + j * 128, q, lane);

    // --- layer 3: 128 -> 1 (fp32), partials in spare cols 128..131 ---
    {
        const float* w3 = W3 + j * 128 + q * 32;   // wave-uniform
        float part = 0.0f;
        #pragma unroll 8
        for (int kk = 0; kk < 32; ++kk) {
            const unsigned int d = X[lane * KP + q * 32 + kk];
            const float xv = __uint_as_float(d << 16)
                           + __uint_as_float(d & 0xffff0000u);
            part = fmaf(xv, w3[kk], part);
        }
        X[lane * KP + 128 + q] = __float_as_uint(part);
    }
    __syncthreads();
    if (t < TILE) {
        const int v = v0 + t;
        const float r = b3[j]
            + __uint_as_float(X[t * KP + 128]) + __uint_as_float(X[t * KP + 129])
            + __uint_as_float(X[t * KP + 130]) + __uint_as_float(X[t * KP + 131]);
        if (v < VN) pred[j * VN + v] = r;
    }
}

// ---------------------------------------------------------------------------
// Kernel 3: softmin blend over J
// ---------------------------------------------------------------------------
__global__ __launch_bounds__(256) void softmin_kernel(const float* __restrict__ pred,
                                                      float* __restrict__ out)
{
    const int v = blockIdx.x * 256 + threadIdx.x;
    if (v >= VN) return;
    float vals[JN];
    float m = 3.4e38f;
    #pragma unroll
    for (int jj = 0; jj < JN; ++jj) {
        vals[jj] = pred[jj * VN + v];
        m = fminf(m, vals[jj]);
    }
    float s1 = 0.0f, s2 = 0.0f;
    #pragma unroll
    for (int jj = 0; jj < JN; ++jj) {
        const float d = vals[jj] - m;
        const float e = __expf(-200.0f * d);
        s1 += e;
        s2 = fmaf(d, e, s2);
    }
    out[v] = s2 / s1 + m;
}

extern "C" void kernel_launch(void* const* d_in, const int* in_sizes, int n_in,
                              void* d_out, int out_size, void* d_ws, size_t ws_size,
                              hipStream_t stream)
{
    const float* pts    = (const float*)d_in[0];
    const float* Bcond  = (const float*)d_in[1];
    const float* Btr    = (const float*)d_in[2];
    const float* Brot   = (const float*)d_in[3];
    const float* Bneigh = (const float*)d_in[4];
    const float* ralpha = (const float*)d_in[5];
    const float* rbeta  = (const float*)d_in[6];
    const float* cW0 = (const float*)d_in[7];
    const float* cb0 = (const float*)d_in[8];
    const float* cW1 = (const float*)d_in[9];
    const float* cb1 = (const float*)d_in[10];
    const float* cW2 = (const float*)d_in[11];
    const float* cb2 = (const float*)d_in[12];
    const float* W0 = (const float*)d_in[13];
    const float* b0 = (const float*)d_in[14];
    const float* W1 = (const float*)d_in[15];
    const float* b1 = (const float*)d_in[16];
    const float* W2 = (const float*)d_in[17];
    const float* b2 = (const float*)d_in[18];
    const float* W3 = (const float*)d_in[19];
    const float* b3 = (const float*)d_in[20];

    float* ws   = (float*)d_ws;
    float* pred = ws;                           // JN*VN floats
    float* c4   = ws + JN * VN;                 // 96
    float* geom = c4 + JN * 4;                  // 576
    unsigned short* wt = (unsigned short*)(geom + JN * 2 * 12);  // 24*139264 ushorts

    setup_kernel<<<WPREP_BLOCKS + JN, 256, 0, stream>>>(
        W0, W1, W2, wt,
        Bcond, Bneigh, ralpha, rbeta,
        cW0, cb0, cW1, cb1, cW2, cb2, c4, geom);

    main_kernel<<<8 * 3 * NXB, 256, 0, stream>>>(pts, Btr, Brot,
                                                 b0, b1, b2, W3, b3,
                                                 c4, geom, wt, pred);

    softmin_kernel<<<(VN + 255) / 256, 256, 0, stream>>>(pred, (float*)d_out);
}

// Round 8
// 254.148 us; speedup vs baseline: 1.0593x; 1.0144x over previous
//
#include <hip/hip_runtime.h>
#include <hip/hip_bf16.h>
#include <math.h>

#define VN 20000
#define JN 24
#define TILE 64
#define KP 132            // packed-activation row pitch in dwords (round-1 proven)
#define EPSF 1e-8f
#define NXB 313           // blocks along V
#define WPREP_BLOCKS 1632 // (JN*17408)/256

typedef __attribute__((ext_vector_type(8))) short bfrag;   // 8 bf16 = 4 VGPRs
typedef __attribute__((ext_vector_type(4))) float f32x4;

// per-joint bf16 weight-plane offsets (ushort units) — doubled-K layout (r5).
// ext slot k_ext = 2*k + {0:hi,1:lo} of the activation. Per layer, TWO B planes:
//   plane A: B[2k]=B[2k+1]=w_hi[k]   -> (ah+al)*bh
//   plane B: B[2k]=w_lo[k], B[2k+1]=0 -> ah*bl
#define WJ_STRIDE 139264
#define L0A 0
#define L0B 4096
#define L1A 8192
#define L1B 40960
#define L2A 73728
#define L2B 106496

__device__ __forceinline__ unsigned short f2bf(float x) {
    __hip_bfloat16 b = __float2bfloat16(x);
    unsigned short u; __builtin_memcpy(&u, &b, 2); return u;
}
__device__ __forceinline__ float bf2f(unsigned short u) {
    __hip_bfloat16 b; __builtin_memcpy(&b, &u, 2);
    return __bfloat162float(b);
}
// pack hi|lo bf16 into one dword: low16 = bf16(x) (half-up hi), high16 = bf16(x-hi)
__device__ __forceinline__ unsigned int pack_hl(float x) {
    const unsigned int h = (__float_as_uint(x) + 0x8000u) & 0xffff0000u;
    const float hf = __uint_as_float(h);
    const float lo = x - hf;
    unsigned int r;
    asm("v_cvt_pk_bf16_f32 %0, %1, %2" : "=v"(r) : "v"(hf), "v"(lo));
    return r;
}

// softplus(100x)/100 with ONE transcendental (validated poly, 9 VALU ops)
__device__ __forceinline__ float softplus_fast(float x) {
    const float u = __builtin_amdgcn_exp2f(-144.269504f * fabsf(x));
    float p = fmaf(u, 3.04480e-4f, -1.31584e-3f);
    p = fmaf(u, p, 2.852768e-3f);
    p = fmaf(u, p, -4.902308e-3f);
    p = fmaf(u, p, 9.992342e-3f);
    p = fmaf(u, p, 8.0e-8f);
    return fmaxf(x, 0.0f) + p;
}

// ---------------------------------------------------------------------------
// Kernel 1 (fused setup): blocks [0, WPREP_BLOCKS) = r5's vectorized weight
// split (verbatim); blocks [WPREP_BLOCKS, +JN) = per-joint prep (r7 verbatim).
// ---------------------------------------------------------------------------
__global__ __launch_bounds__(256) void setup_kernel(
    const float* __restrict__ W0, const float* __restrict__ W1,
    const float* __restrict__ W2, unsigned short* __restrict__ wt,
    const float* __restrict__ Bcond, const float* __restrict__ Bneigh,
    const float* __restrict__ ralpha, const float* __restrict__ rbeta,
    const float* __restrict__ cW0, const float* __restrict__ cb0,
    const float* __restrict__ cW1, const float* __restrict__ cb1,
    const float* __restrict__ cW2, const float* __restrict__ cb2,
    float* __restrict__ c4, float* __restrict__ geom)
{
    if (blockIdx.x < WPREP_BLOCKS) {
        // ---- wprep (r5 verbatim): 8 ushorts (16B) per thread ----
        const int g = blockIdx.x * 256 + threadIdx.x;      // < 24*17408
        const int jj = g / 17408;
        const int r = (g - jj * 17408) * 8;                // ushort base within joint
        const float* src; int kin, pr; bool loP;
        if (r < 8192)       { src = W0 + jj * 896;   kin = 7;   pr = r & 4095;          loP = r >= L0B; }
        else if (r < 73728) { src = W1 + jj * 16384; kin = 128; pr = (r - L1A) & 32767; loP = r >= L1B; }
        else                { src = W2 + jj * 16384; kin = 128; pr = (r - L2A) & 32767; loP = r >= L2B; }
        const int lane = (pr >> 3) & 63;
        const int nt   = (pr >> 9) & 7;
        const int ks   = pr >> 12;
        const int n  = nt * 16 + (lane & 15);
        const int k0 = (ks * 32 + (lane >> 4) * 8) >> 1;   // even base / 2
        unsigned short out[8];
        #pragma unroll
        for (int kk = 0; kk < 4; ++kk) {
            const float v = (k0 + kk < kin) ? src[(k0 + kk) * 128 + n] : 0.0f;
            const unsigned short h = f2bf(v);
            if (!loP) { out[2*kk] = h; out[2*kk+1] = h; }
            else      { out[2*kk] = f2bf(v - bf2f(h)); out[2*kk+1] = 0; }
        }
        *(uint4*)(wt + jj * WJ_STRIDE + r) = *(const uint4*)out;
        return;
    }

    // ---- prep: one block per joint ----
    __shared__ float cond_s[288];
    __shared__ float sh[16][17];
    __shared__ float hb[16];
    const int j = blockIdx.x - WPREP_BLOCKS;   // 0..23
    const int t = threadIdx.x;

    for (int i = t; i < 288; i += 256) cond_s[i] = Bcond[j * 288 + i];

    if (t < 2) {
        const int gi = t;
        const float* nb = Bneigh + (j * 2 + gi) * 15;
        const float tx = nb[0],  ty = nb[1],  tz = nb[2];
        const float cx = nb[3],  cy = nb[4],  cz = nb[5];
        const float ox = nb[6],  oy = nb[7],  oz = nb[8];
        const float px = nb[9],  py = nb[10], pz = nb[11];
        const int bid_this  = (int)nb[12];
        const int bid_other = (int)nb[13];
        const float xa_n = ralpha[bid_other * JN + bid_this] - 1.0f;
        const float xa_s = ralpha[bid_this * JN + bid_other] - 1.0f;
        const float a_n = xa_n > 0.0f ? xa_n + 1.0f : expf(xa_n);
        const float a_s = xa_s > 0.0f ? xa_s + 1.0f : expf(xa_s);
        const float be_n = rbeta[bid_other * JN + bid_this];
        const float be_s = rbeta[bid_this * JN + bid_other];

        const float bnx = ox - cx, bny = oy - cy, bnz = oz - cz;
        const float bsx = tx - cx, bsy = ty - cy, bsz = tz - cz;
        const float nb_n = sqrtf(bnx*bnx + bny*bny + bnz*bnz);
        const float nb_s = sqrtf(bsx*bsx + bsy*bsy + bsz*bsz);
        const float f = nb_n / (nb_n + nb_s + EPSF);
        const float vbnx = (ox - tx) * f, vbny = (oy - ty) * f, vbnz = (oz - tz) * f;
        const float g2 = -nb_s / (nb_n + EPSF);
        const float vbsx = vbnx * g2, vbsy = vbny * g2, vbsz = vbnz * g2;
        const float n_n = sqrtf(vbnx*vbnx + vbny*vbny + vbnz*vbnz);
        const float n_s = sqrtf(vbsx*vbsx + vbsy*vbsy + vbsz*vbsz);
        const float trx = ox - vbnx, tr_y = oy - vbny, trz = oz - vbnz;
        const float inn = 1.0f / ((n_n + EPSF) * (n_n + EPSF));
        const float ins = 1.0f / ((n_s + EPSF) * (n_s + EPSF));
        const float gx = vbnx * inn * a_n - vbsx * ins * a_s;
        const float gy = vbny * inn * a_n - vbsy * ins * a_s;
        const float gz = vbnz * inn * a_n - vbsz * ins * a_s;
        const float h = -(trx * gx + tr_y * gy + trz * gz) + be_n - be_s;
        float* gm = geom + (j * 2 + gi) * 12;
        gm[0] = gx; gm[1] = gy; gm[2] = gz; gm[3] = h;
        gm[4] = px; gm[5] = py; gm[6] = pz;
        gm[7] = cx; gm[8] = cy; gm[9] = cz;
        gm[10] = 0.0f; gm[11] = 0.0f;
    }
    __syncthreads();

    // cMLP L0: 16 outputs x 16 chunks of 18
    {
        const int o = t & 15, c = t >> 4;
        const float* w = cW0 + j * 288 * 16 + o;
        const int d0 = c * 18;
        float acc = 0.0f;
        #pragma unroll
        for (int d = 0; d < 18; ++d) acc = fmaf(cond_s[d0 + d], w[(d0 + d) * 16], acc);
        sh[c][o] = acc;
    }
    __syncthreads();
    if (t < 16) {
        float acc = cb0[j * 16 + t];
        #pragma unroll
        for (int c = 0; c < 16; ++c) acc += sh[c][t];
        hb[t] = softplus_fast(acc);
    }
    __syncthreads();
    if (t < 16) {
        const float* w = cW1 + j * 256 + t;
        float acc = cb1[j * 16 + t];
        #pragma unroll
        for (int d = 0; d < 16; ++d) acc = fmaf(hb[d], w[d * 16], acc);
        sh[0][t] = softplus_fast(acc);
    }
    __syncthreads();
    if (t < 4) {
        const float* w = cW2 + j * 64 + t;
        float acc = cb2[j * 4 + t];
        #pragma unroll
        for (int d = 0; d < 16; ++d) acc = fmaf(sh[0][d], w[d * 4], acc);
        c4[j * 4 + t] = acc;
    }
}

// ---------------------------------------------------------------------------
// Kernel 2: main — r7 structure; FIXED decode: j changes SLOWEST within an
// XCD (j = xcd*3 + s/313, x = s%313) so co-resident same-CU blocks share j
// (L1 weight reuse, the r5 property) while each XCD touches only 3 joints
// (L2 confinement, the r7 property).
// ---------------------------------------------------------------------------
template<int NKS>
__device__ __forceinline__ void mfma_layer(
    unsigned int* __restrict__ X,
    const unsigned short* __restrict__ wA,
    const unsigned short* __restrict__ wB,
    const float* __restrict__ bvec,
    int q, int lane)
{
    const int l = lane & 15;
    const int quad = lane >> 4;
    const float bia0 = bvec[q * 32 + l];        // ni=0 channel bias (col l)
    const float bia1 = bvec[q * 32 + 16 + l];   // ni=1
    f32x4 acc[4][2];
    #pragma unroll
    for (int mi = 0; mi < 4; ++mi) {
        acc[mi][0] = (f32x4){bia0, bia0, bia0, bia0};
        acc[mi][1] = (f32x4){bia1, bia1, bia1, bia1};
    }

    #pragma unroll 2
    for (int ks = 0; ks < NKS; ++ks) {
        bfrag bA[2], bB[2];
        #pragma unroll
        for (int ni = 0; ni < 2; ++ni) {
            const int off = ((ks * 8 + (q * 2 + ni)) * 64 + lane) * 8;
            bA[ni] = *(const bfrag*)(wA + off);   // coalesced 16B/lane
            bB[ni] = *(const bfrag*)(wB + off);
        }
        #pragma unroll
        for (int mi = 0; mi < 4; ++mi) {
            // ext slots ks*32 + quad*8 + [0..7] == dwords ks*16 + quad*4 + [0..3]
            const bfrag a = *(const bfrag*)(
                (const unsigned short*)(X + (mi * 16 + l) * KP) + ks * 32 + quad * 8);
            #pragma unroll
            for (int ni = 0; ni < 2; ++ni) {
                acc[mi][ni] = __builtin_amdgcn_mfma_f32_16x16x32_bf16(a, bA[ni], acc[mi][ni], 0, 0, 0);
                acc[mi][ni] = __builtin_amdgcn_mfma_f32_16x16x32_bf16(a, bB[ni], acc[mi][ni], 0, 0, 0);
            }
        }
    }
    __syncthreads();   // all A reads done before overwrite
    #pragma unroll
    for (int ni = 0; ni < 2; ++ni) {
        const int ch = q * 32 + ni * 16 + l;
        #pragma unroll
        for (int mi = 0; mi < 4; ++mi) {
            #pragma unroll
            for (int r = 0; r < 4; ++r) {
                const float v = softplus_fast(acc[mi][ni][r]);
                const int p = mi * 16 + quad * 4 + r;
                X[p * KP + ch] = pack_hl(v);
            }
        }
    }
    __syncthreads();
}

__global__ __launch_bounds__(256, 4) void main_kernel(
    const float* __restrict__ pts, const float* __restrict__ Btr,
    const float* __restrict__ Brot,
    const float* __restrict__ b0, const float* __restrict__ b1,
    const float* __restrict__ b2, const float* __restrict__ W3,
    const float* __restrict__ b3,
    const float* __restrict__ c4, const float* __restrict__ geom,
    const unsigned short* __restrict__ wt,
    float* __restrict__ pred)
{
    __shared__ unsigned int X[TILE * KP];
    // XCD-aware decode, j slowest within XCD:
    // bid = xcd + 8*s, s = jloc*313 + x; j = xcd*3 + jloc
    const int bid = blockIdx.x;
    const int xcd = bid & 7;
    const int s = bid >> 3;          // 0..938
    const int jloc = s / NXB;        // 0..2
    const int j = xcd * 3 + jloc;
    const int v0 = (s - jloc * NXB) * TILE;
    const int t = threadIdx.x;
    const int lane = t & 63;
    const int q = __builtin_amdgcn_readfirstlane(t >> 6);

    // --- phase 0: local coords + neighbor deformation -> packed input rows ---
    if (t < TILE) {
        const int v = v0 + t;
        float plx = 0.0f, ply = 0.0f, plz = 0.0f;
        if (v < VN) {
            const float dx = pts[v * 3 + 0] - Btr[j * 3 + 0];
            const float dy = pts[v * 3 + 1] - Btr[j * 3 + 1];
            const float dz = pts[v * 3 + 2] - Btr[j * 3 + 2];
            const float* R = Brot + j * 9;
            plx = R[0] * dx + R[3] * dy + R[6] * dz;
            ply = R[1] * dx + R[4] * dy + R[7] * dz;
            plz = R[2] * dx + R[5] * dy + R[8] * dz;
            float osx = 0.0f, osy = 0.0f, osz = 0.0f;
            #pragma unroll
            for (int gi = 0; gi < 2; ++gi) {
                const float* gm = geom + (j * 2 + gi) * 12;
                const float arg = plx * gm[0] + ply * gm[1] + plz * gm[2] + gm[3];
                const float w = 1.0f / (1.0f + __expf(-arg));
                const float aax = -gm[4] * w, aay = -gm[5] * w, aaz = -gm[6] * w;
                const float jcx = gm[7], jcy = gm[8], jcz = gm[9];
                const float ang = sqrtf(aax * aax + aay * aay + aaz * aaz);
                const float inv = ang < 1e-12f ? 1.0f : 1.0f / ang;
                const float ux = aax * inv, uy = aay * inv, uz = aaz * inv;
                const float co = __cosf(ang), si = __sinf(ang), C = 1.0f - co;
                const float vx = plx - jcx, vy = ply - jcy, vz = plz - jcz;
                const float du = ux * vx + uy * vy + uz * vz;
                const float cxv = uy * vz - uz * vy;
                const float cyv = uz * vx - ux * vz;
                const float czv = ux * vy - uy * vx;
                float offx = co * vx + si * cxv + C * ux * du + jcx - plx;
                float offy = co * vy + si * cyv + C * uy * du + jcy - ply;
                float offz = co * vz + si * czv + C * uz * du + jcz - plz;
                if (isnan(offx)) offx = 0.0f;
                if (isnan(offy)) offy = 0.0f;
                if (isnan(offz)) offz = 0.0f;
                osx += offx; osy += offy; osz += offz;
            }
            plx += osx; ply += osy; plz += osz;
        }
        X[t * KP + 0] = pack_hl(plx);
        X[t * KP + 1] = pack_hl(ply);
        X[t * KP + 2] = pack_hl(plz);
        X[t * KP + 3] = pack_hl(c4[j * 4 + 0]);
        X[t * KP + 4] = pack_hl(c4[j * 4 + 1]);
        X[t * KP + 5] = pack_hl(c4[j * 4 + 2]);
        X[t * KP + 6] = pack_hl(c4[j * 4 + 3]);
        // layer-0 A reads touch dwords 0..15 only (ext K=32)
        #pragma unroll
        for (int k = 7; k < 16; ++k) X[t * KP + k] = 0u;
    }
    __syncthreads();

    const unsigned short* wj = wt + j * WJ_STRIDE;
    mfma_layer<1>(X, wj + L0A, wj + L0B, b0 + j * 128, q, lane);
    mfma_layer<8>(X, wj + L1A, wj + L1B, b1 + j * 128, q, lane);
    mfma_layer<8>(X, wj + L2A, wj + L2B, b2 + j * 128, q, lane);

    // --- layer 3: 128 -> 1 (fp32), partials in spare cols 128..131 ---
    {
        const float* w3 = W3 + j * 128 + q * 32;   // wave-uniform
        float part = 0.0f;
        #pragma unroll 8
        for (int kk = 0; kk < 32; ++kk) {
            const unsigned int d = X[lane * KP + q * 32 + kk];
            const float xv = __uint_as_float(d << 16)
                           + __uint_as_float(d & 0xffff0000u);
            part = fmaf(xv, w3[kk], part);
        }
        X[lane * KP + 128 + q] = __float_as_uint(part);
    }
    __syncthreads();
    if (t < TILE) {
        const int v = v0 + t;
        const float r = b3[j]
            + __uint_as_float(X[t * KP + 128]) + __uint_as_float(X[t * KP + 129])
            + __uint_as_float(X[t * KP + 130]) + __uint_as_float(X[t * KP + 131]);
        if (v < VN) pred[j * VN + v] = r;
    }
}

// ---------------------------------------------------------------------------
// Kernel 3: softmin blend over J
// ---------------------------------------------------------------------------
__global__ __launch_bounds__(256) void softmin_kernel(const float* __restrict__ pred,
                                                      float* __restrict__ out)
{
    const int v = blockIdx.x * 256 + threadIdx.x;
    if (v >= VN) return;
    float vals[JN];
    float m = 3.4e38f;
    #pragma unroll
    for (int jj = 0; jj < JN; ++jj) {
        vals[jj] = pred[jj * VN + v];
        m = fminf(m, vals[jj]);
    }
    float s1 = 0.0f, s2 = 0.0f;
    #pragma unroll
    for (int jj = 0; jj < JN; ++jj) {
        const float d = vals[jj] - m;
        const float e = __expf(-200.0f * d);
        s1 += e;
        s2 = fmaf(d, e, s2);
    }
    out[v] = s2 / s1 + m;
}

extern "C" void kernel_launch(void* const* d_in, const int* in_sizes, int n_in,
                              void* d_out, int out_size, void* d_ws, size_t ws_size,
                              hipStream_t stream)
{
    const float* pts    = (const float*)d_in[0];
    const float* Bcond  = (const float*)d_in[1];
    const float* Btr    = (const float*)d_in[2];
    const float* Brot   = (const float*)d_in[3];
    const float* Bneigh = (const float*)d_in[4];
    const float* ralpha = (const float*)d_in[5];
    const float* rbeta  = (const float*)d_in[6];
    const float* cW0 = (const float*)d_in[7];
    const float* cb0 = (const float*)d_in[8];
    const float* cW1 = (const float*)d_in[9];
    const float* cb1 = (const float*)d_in[10];
    const float* cW2 = (const float*)d_in[11];
    const float* cb2 = (const float*)d_in[12];
    const float* W0 = (const float*)d_in[13];
    const float* b0 = (const float*)d_in[14];
    const float* W1 = (const float*)d_in[15];
    const float* b1 = (const float*)d_in[16];
    const float* W2 = (const float*)d_in[17];
    const float* b2 = (const float*)d_in[18];
    const float* W3 = (const float*)d_in[19];
    const float* b3 = (const float*)d_in[20];

    float* ws   = (float*)d_ws;
    float* pred = ws;                           // JN*VN floats
    float* c4   = ws + JN * VN;                 // 96
    float* geom = c4 + JN * 4;                  // 576
    unsigned short* wt = (unsigned short*)(geom + JN * 2 * 12);  // 24*139264 ushorts

    setup_kernel<<<WPREP_BLOCKS + JN, 256, 0, stream>>>(
        W0, W1, W2, wt,
        Bcond, Bneigh, ralpha, rbeta,
        cW0, cb0, cW1, cb1, cW2, cb2, c4, geom);

    main_kernel<<<8 * 3 * NXB, 256, 0, stream>>>(pts, Btr, Brot,
                                                 b0, b1, b2, W3, b3,
                                                 c4, geom, wt, pred);

    softmin_kernel<<<(VN + 255) / 256, 256, 0, stream>>>(pred, (float*)d_out);
}